// Round 17
// baseline (652.240 us; speedup 1.0000x reference)
//
#include <hip/hip_runtime.h>
#include <hip/hip_bf16.h>

#define EPS 1e-6f
#define SCAL 5.0f

typedef __attribute__((ext_vector_type(8))) short bf8v;   // 8 bf16 (4 VGPRs)
typedef __attribute__((ext_vector_type(4))) float f32x4;  // MFMA acc

// ---- workspace (float units) ----
#define OFF_MU     0
#define OFF_LINV   1024
#define OFF_MUA    3072
#define OFF_LINVA  4096
#define OFF_HSUM   6144
#define OFF_ALPHA  6656
#define OFF_REC    23040
#define OFF_R1     32768
#define OFF_R2     (OFF_R1 + 8388608)
#define OFF_R3     (OFF_R2 + 8388608)
#define WS_TOTAL   (OFF_R3 + 16777216)

// NHWC bf16 tensors (offsets in bf16 elements) and fp32 tensors (float offsets)
#define BA_XA   ((size_t)2 * OFF_R3)            // conv1 out [64,4096,64]
#define BA_X2   ((size_t)2 * OFF_R1)            // conv2 out [64,4096,64]
#define OFF_PARTSF OFF_R2                        // parts logits fp32 [64,4096,16]
#define OFF_PROBS  (OFF_R2 + 4194304)            // app probs fp32 [32,16,4096]
#define BA_EA1  ((size_t)2 * OFF_R3)            // ea1 out [32,4096,64]
#define OFF_FXS (OFF_R3 + 4194304)              // f_xs fp32 [32,4096,32]
#define BA_E    ((size_t)2 * OFF_R2)            // encoding [32,4096,64] (48 real + 16 pad)
#define BA_D1   ((size_t)2 * OFF_R1)            // dw1 out [32,4096,64]
#define BA_D2   ((size_t)2 * OFF_R3)            // upconv out [32,16384,32]

// g_wt fp32 layout
#define WT_ESW1 0
#define WT_ESB1 1728
#define WT_ESB2 1792
#define WT_ESBP 1856
#define WT_EAB1 1872
#define WT_EAB2 1936
#define WT_DB1  1968
#define WT_DB2  2032
#define WT_W3P  2064
#define WT_DB3  2928
// g_wp bf16 packed weights [tap][oc][ic]
#define P_WP2  0
#define P_WPP  36864
#define P_WPA1 46080
#define P_WPA2 82944
#define P_WPD1 101376
#define P_WPD2 138240

__device__ __attribute__((aligned(16))) float g_ws[WS_TOTAL];
__device__ __attribute__((aligned(16))) float g_wt[3072];
__device__ __attribute__((aligned(16))) __hip_bfloat16 g_wp[156672];
__device__ int g_isbf16;

__device__ __forceinline__ float selz(bool c, float v) { return c ? v : 0.f; }
__device__ __forceinline__ float cvtbf(short s) {
    return __uint_as_float(((unsigned int)(unsigned short)s) << 16);
}
// runtime-dtype external load (adaptive — fixed-dtype builds NaN'd in rounds 1/2/7)
__device__ __forceinline__ float ldin(const void* p, size_t i, int bf) {
    return bf ? __bfloat162float(((const __hip_bfloat16*)p)[i])
              : ((const float*)p)[i];
}

// ---------------- block reductions (blockDim.x == 256) ----------------
__device__ __forceinline__ float block_sum(float v) {
    __shared__ float sb[8];
    for (int off = 32; off; off >>= 1) v += __shfl_down(v, off, 64);
    int lane = threadIdx.x & 63, wid = threadIdx.x >> 6;
    __syncthreads();
    if (lane == 0) sb[wid] = v;
    __syncthreads();
    float r = 0.f;
    for (int i = 0; i < 4; ++i) r += sb[i];
    return r;
}
__device__ __forceinline__ float block_max(float v) {
    __shared__ float sb[8];
    for (int off = 32; off; off >>= 1) v = fmaxf(v, __shfl_down(v, off, 64));
    int lane = threadIdx.x & 63, wid = threadIdx.x >> 6;
    __syncthreads();
    if (lane == 0) sb[wid] = v;
    __syncthreads();
    float r = -1e30f;
    for (int i = 0; i < 4; ++i) r = fmaxf(r, sb[i]);
    return r;
}

// ---------------- dtype probe + init ----------------
__global__ void detect_k(const void* x) {
    const __hip_bfloat16* p = (const __hip_bfloat16*)x;
    int lane = threadIdx.x & 63;
    float v = 0.f;
    for (int i = lane; i < 256; i += 64) {
        float a = fabsf(__bfloat162float(p[i]));
        if (!(a <= 2.0f)) v = 1.f;
    }
    for (int off = 32; off; off >>= 1) v += __shfl_down(v, off, 64);
    if (lane == 0) {
        g_isbf16 = (v == 0.f) ? 1 : 0;
        g_ws[OFF_REC] = 0.f;
    }
}

// ---------------- weight pack: ext dtype -> g_wt fp32 + g_wp bf16 [t][n][k] ----------------
__global__ void wpack_k(const void* esw1, const void* esb1, const void* esw2, const void* esb2,
                        const void* eswp, const void* esbp, const void* eaw1, const void* eab1,
                        const void* eaw2, const void* eab2, const void* dw1, const void* db1,
                        const void* dw2, const void* db2, const void* dw3, const void* db3) {
    int bf = g_isbf16;
    int gid0 = blockIdx.x * 256 + threadIdx.x, stride = gridDim.x * 256;
    for (int g = gid0; g < 1728; g += stride) g_wt[WT_ESW1 + g] = ldin(esw1, g, bf);
    for (int g = gid0; g < 64; g += stride) g_wt[WT_ESB1 + g] = ldin(esb1, g, bf);
    for (int g = gid0; g < 64; g += stride) g_wt[WT_ESB2 + g] = ldin(esb2, g, bf);
    for (int g = gid0; g < 16; g += stride) g_wt[WT_ESBP + g] = ldin(esbp, g, bf);
    for (int g = gid0; g < 64; g += stride) g_wt[WT_EAB1 + g] = ldin(eab1, g, bf);
    for (int g = gid0; g < 32; g += stride) g_wt[WT_EAB2 + g] = ldin(eab2, g, bf);
    for (int g = gid0; g < 64; g += stride) g_wt[WT_DB1 + g] = ldin(db1, g, bf);
    for (int g = gid0; g < 32; g += stride) g_wt[WT_DB2 + g] = ldin(db2, g, bf);
    for (int g = gid0; g < 3; g += stride) g_wt[WT_DB3 + g] = ldin(db3, g, bf);
    for (int g = gid0; g < 864; g += stride) {              // w3p[t][o][k]
        int t = g / 96, o = (g / 32) % 3, k = g & 31;
        g_wt[WT_W3P + g] = ldin(dw3, (size_t)(o * 32 + k) * 9 + t, bf);
    }
    for (int g = gid0; g < 36864; g += stride) {            // wp2[t][n][k] from es_w2[n][k][t]
        int t = g >> 12, n = (g >> 6) & 63, k = g & 63;
        g_wp[P_WP2 + g] = __float2bfloat16(ldin(esw2, (size_t)(n * 64 + k) * 9 + t, bf));
    }
    for (int g = gid0; g < 9216; g += stride) {             // wpp[t][n<16][k]
        int t = g >> 10, n = (g >> 6) & 15, k = g & 63;
        g_wp[P_WPP + g] = __float2bfloat16(ldin(eswp, (size_t)(n * 64 + k) * 9 + t, bf));
    }
    for (int g = gid0; g < 36864; g += stride) {            // wpa1
        int t = g >> 12, n = (g >> 6) & 63, k = g & 63;
        g_wp[P_WPA1 + g] = __float2bfloat16(ldin(eaw1, (size_t)(n * 64 + k) * 9 + t, bf));
    }
    for (int g = gid0; g < 18432; g += stride) {            // wpa2[t][n<32][k]
        int t = g >> 11, n = (g >> 6) & 31, k = g & 63;
        g_wp[P_WPA2 + g] = __float2bfloat16(ldin(eaw2, (size_t)(n * 64 + k) * 9 + t, bf));
    }
    for (int g = gid0; g < 36864; g += stride) {            // wpd1: K=48 zero-padded to 64
        int t = g >> 12, n = (g >> 6) & 63, k = g & 63;
        float v = (k < 48) ? ldin(dw1, (size_t)(n * 48 + k) * 9 + t, bf) : 0.f;
        g_wp[P_WPD1 + g] = __float2bfloat16(v);
    }
    for (int g = gid0; g < 18432; g += stride) {            // wpd2[t][n<32][k]
        int t = g >> 11, n = (g >> 6) & 31, k = g & 63;
        g_wp[P_WPD2 + g] = __float2bfloat16(ldin(dw2, (size_t)(n * 64 + k) * 9 + t, bf));
    }
}

// ---------------- conv1 both streams: stride-2 -> NHWC bf16 [64,4096,64], relu ----
__global__ void __launch_bounds__(256)
conv_s2n_k(const void* __restrict__ inA, const void* __restrict__ inB) {
    int bf = g_isbf16;
    int tile = blockIdx.x & 15;
    int gb = blockIdx.x >> 4;
    int g = gb & 3, b = gb >> 2;
    const void* in = (b < 32) ? inA : inB;
    int bb = b & 31;
    int pix = tile * 256 + threadIdx.x;
    int y = pix >> 6, x = pix & 63;
    size_t inb = (size_t)bb * 3 * 16384;
    const float* W = g_wt + WT_ESW1 + (size_t)(g * 16) * 27;
    float acc[16];
    #pragma unroll
    for (int o = 0; o < 16; ++o) acc[o] = g_wt[WT_ESB1 + g * 16 + o];
    int iy0 = 2 * y, ix0 = 2 * x;
    bool my2 = (iy0 + 2 < 128), mx2 = (ix0 + 2 < 128);
    int iy2 = my2 ? iy0 + 2 : 127, ix2 = mx2 ? ix0 + 2 : 127;
    for (int ic = 0; ic < 3; ++ic) {
        size_t pb = inb + ic * 16384;
        float t[9];
        t[0] = ldin(in, pb + iy0 * 128 + ix0, bf);
        t[1] = ldin(in, pb + iy0 * 128 + ix0 + 1, bf);
        t[2] = selz(mx2, ldin(in, pb + iy0 * 128 + ix2, bf));
        t[3] = ldin(in, pb + (iy0 + 1) * 128 + ix0, bf);
        t[4] = ldin(in, pb + (iy0 + 1) * 128 + ix0 + 1, bf);
        t[5] = selz(mx2, ldin(in, pb + (iy0 + 1) * 128 + ix2, bf));
        t[6] = selz(my2, ldin(in, pb + iy2 * 128 + ix0, bf));
        t[7] = selz(my2, ldin(in, pb + iy2 * 128 + ix0 + 1, bf));
        t[8] = selz(my2 && mx2, ldin(in, pb + iy2 * 128 + ix2, bf));
        #pragma unroll
        for (int o = 0; o < 16; ++o) {
            const float* wr = W + (o * 3 + ic) * 9;
            float a = acc[o];
            #pragma unroll
            for (int j = 0; j < 9; ++j) a = fmaf(t[j], wr[j], a);
            acc[o] = a;
        }
    }
    __hip_bfloat16* out = (__hip_bfloat16*)g_ws + BA_XA + ((size_t)b * 4096 + pix) * 64 + g * 16;
    #pragma unroll
    for (int o = 0; o < 16; ++o) out[o] = __float2bfloat16(fmaxf(acc[o], 0.f));
}

// ---------------- MFMA 3x3 conv on 64x64 NHWC (Cin=64) ----------------
// TOTN = total ocs; each wave: 1 row x NS*16 ocs; TOTN/(16*NS) waves per row.
// A[m=lane&15][k=quad*8+j]; B[k][n=lane&15]; C col=lane&15 row=quad*4+reg
template<int TOTN, int NS, int OUTF32, int RELU>
__global__ void __launch_bounds__(256) __attribute__((amdgpu_waves_per_eu(2)))
conv_mf_k(size_t in_off, int wp_off, int bias_off, size_t out_off) {
    constexpr int WPR = TOTN / (NS * 16);
    int wid = threadIdx.x >> 6, lane = threadIdx.x & 63;
    int l15 = lane & 15, quad = lane >> 4;
    int job = blockIdx.x * 4 + wid;
    int row = job / WPR;
    int ocb = (job % WPR) * NS * 16;
    int b = row >> 6, y = row & 63;
    const __hip_bfloat16* inb = (const __hip_bfloat16*)g_ws + in_off + (size_t)b * 4096 * 64;
    f32x4 acc[4][NS];
    #pragma unroll
    for (int ms = 0; ms < 4; ++ms)
        #pragma unroll
        for (int ns = 0; ns < NS; ++ns) acc[ms][ns] = (f32x4){0.f, 0.f, 0.f, 0.f};
    #pragma unroll
    for (int t = 0; t < 9; ++t) {
        int dy = t / 3 - 1, dx = t % 3 - 1;
        int yy = y + dy;
        if (yy < 0 || yy > 63) continue;
        #pragma unroll
        for (int c = 0; c < 2; ++c) {
            bf8v a[4];
            #pragma unroll
            for (int ms = 0; ms < 4; ++ms) {
                int xx = ms * 16 + l15 + dx;
                bool v = (xx >= 0 && xx < 64);
                int xc = v ? xx : 0;
                bf8v av = *(const bf8v*)(inb + ((size_t)(yy * 64 + xc) * 64 + c * 32 + quad * 8));
                if (!v) av = (bf8v){0, 0, 0, 0, 0, 0, 0, 0};
                a[ms] = av;
            }
            #pragma unroll
            for (int ns = 0; ns < NS; ++ns) {
                bf8v bv = *(const bf8v*)(g_wp + wp_off +
                          ((size_t)(t * TOTN + ocb + ns * 16 + l15) * 64 + c * 32 + quad * 8));
                #pragma unroll
                for (int ms = 0; ms < 4; ++ms)
                    acc[ms][ns] = __builtin_amdgcn_mfma_f32_16x16x32_bf16(a[ms], bv, acc[ms][ns], 0, 0, 0);
            }
        }
    }
    #pragma unroll
    for (int ns = 0; ns < NS; ++ns) {
        float bias = g_wt[bias_off + ocb + ns * 16 + l15];
        #pragma unroll
        for (int ms = 0; ms < 4; ++ms) {
            #pragma unroll
            for (int r = 0; r < 4; ++r) {
                int pix = ms * 16 + quad * 4 + r;
                float v = acc[ms][ns][r] + bias;
                if (RELU) v = fmaxf(v, 0.f);
                size_t o = out_off + ((size_t)(b * 4096 + y * 64 + pix)) * TOTN + ocb + ns * 16 + l15;
                if (OUTF32) g_ws[o] = v;
                else ((__hip_bfloat16*)g_ws)[o] = __float2bfloat16(v);
            }
        }
    }
}

// ---------------- MFMA decoder conv2 + 2x upsample: wave = half out-row (64px) x 32 ocs ----
__global__ void __launch_bounds__(256) __attribute__((amdgpu_waves_per_eu(2)))
conv_upmf_k(size_t in_off, int wp_off, int bias_off, size_t out_off) {
    int wid = threadIdx.x >> 6, lane = threadIdx.x & 63;
    int l15 = lane & 15, quad = lane >> 4;
    int job = blockIdx.x * 4 + wid;
    int part = job & 1;
    int row = job >> 1;
    int b = row >> 7, y = row & 127;
    int xb = part * 64;
    const __hip_bfloat16* inb = (const __hip_bfloat16*)g_ws + in_off + (size_t)b * 4096 * 64;
    f32x4 acc[4][2];
    #pragma unroll
    for (int ms = 0; ms < 4; ++ms)
        #pragma unroll
        for (int ns = 0; ns < 2; ++ns) acc[ms][ns] = (f32x4){0.f, 0.f, 0.f, 0.f};
    #pragma unroll
    for (int t = 0; t < 9; ++t) {
        int dy = t / 3 - 1, dx = t % 3 - 1;
        int yy = y + dy;
        if (yy < 0 || yy > 127) continue;
        int yi = yy >> 1;
        #pragma unroll
        for (int c = 0; c < 2; ++c) {
            bf8v a[4];
            #pragma unroll
            for (int ms = 0; ms < 4; ++ms) {
                int xx = xb + ms * 16 + l15 + dx;
                bool v = (xx >= 0 && xx < 128);
                int xi = (v ? xx : 0) >> 1;
                bf8v av = *(const bf8v*)(inb + ((size_t)(yi * 64 + xi) * 64 + c * 32 + quad * 8));
                if (!v) av = (bf8v){0, 0, 0, 0, 0, 0, 0, 0};
                a[ms] = av;
            }
            #pragma unroll
            for (int ns = 0; ns < 2; ++ns) {
                bf8v bv = *(const bf8v*)(g_wp + wp_off +
                          ((size_t)(t * 32 + ns * 16 + l15) * 64 + c * 32 + quad * 8));
                #pragma unroll
                for (int ms = 0; ms < 4; ++ms)
                    acc[ms][ns] = __builtin_amdgcn_mfma_f32_16x16x32_bf16(a[ms], bv, acc[ms][ns], 0, 0, 0);
            }
        }
    }
    #pragma unroll
    for (int ns = 0; ns < 2; ++ns) {
        float bias = g_wt[bias_off + ns * 16 + l15];
        #pragma unroll
        for (int ms = 0; ms < 4; ++ms) {
            #pragma unroll
            for (int r = 0; r < 4; ++r) {
                int pix = xb + ms * 16 + quad * 4 + r;
                float v = fmaxf(acc[ms][ns][r] + bias, 0.f);
                size_t o = out_off + ((size_t)(b * 16384 + y * 128 + pix)) * 32 + ns * 16 + l15;
                ((__hip_bfloat16*)g_ws)[o] = __float2bfloat16(v);
            }
        }
    }
}

// ---------------- fused softmax+moments: parts logits fp32 NHWC [64,4096,16] ----------------
__global__ void sm_mom3_k() {
    int bk = blockIdx.x;
    int b = bk >> 4, k = bk & 15;
    int app = (b >= 32);
    const float* P = g_ws + OFF_PARTSF + (size_t)b * 4096 * 16 + k;
    float r[16];
    #pragma unroll
    for (int j = 0; j < 16; ++j) r[j] = P[(size_t)(threadIdx.x + j * 256) * 16];
    float m = r[0];
    #pragma unroll
    for (int j = 1; j < 16; ++j) m = fmaxf(m, r[j]);
    m = block_max(m);
    float s = 0.f;
    #pragma unroll
    for (int j = 0; j < 16; ++j) { r[j] = __expf(r[j] - m); s += r[j]; }
    s = block_sum(s);
    float inv = 1.0f / s;
    float sy = 0, sx = 0, syy = 0, sxy = 0, sxx = 0;
    #pragma unroll
    for (int j = 0; j < 16; ++j) {
        float pv = r[j] * inv;
        int i = threadIdx.x + j * 256;
        if (app) g_ws[OFF_PROBS + ((size_t)(b - 32) * 16 + k) * 4096 + i] = pv;
        float gy = -1.0f + (i >> 6) * (2.0f / 63.0f);
        float gx = -1.0f + (i & 63) * (2.0f / 63.0f);
        sy += pv * gy; sx += pv * gx;
        syy += pv * gy * gy; sxy += pv * gy * gx; sxx += pv * gx * gx;
    }
    sy = block_sum(sy); sx = block_sum(sx);
    syy = block_sum(syy); sxy = block_sum(sxy); sxx = block_sum(sxx);
    if (threadIdx.x == 0) {
        float c00 = syy - sy * sy, c01 = sxy - sy * sx, c11 = sxx - sx * sx;
        float a = sqrtf(fmaxf(c00 + EPS, 1e-12f));
        float bb = c01 / (a + EPS);
        float cc = sqrtf(fmaxf(c11 - bb * bb, 0.f) + EPS);
        float det = a * cc;
        float sc = SCAL / (det + EPS);
        int idx = app ? ((b - 32) * 16 + k) : (b * 16 + k);
        int mu_off = app ? OFF_MUA : OFF_MU;
        int linv_off = app ? OFF_LINVA : OFF_LINV;
        g_ws[mu_off + idx * 2 + 0] = sy;
        g_ws[mu_off + idx * 2 + 1] = sx;
        g_ws[linv_off + idx * 4 + 0] = cc * sc;
        g_ws[linv_off + idx * 4 + 1] = 0.f;
        g_ws[linv_off + idx * 4 + 2] = -bb * sc;
        g_ws[linv_off + idx * 4 + 3] = a * sc;
    }
}

// ---------------- alpha[b,k,f] = sum_hw probs[b,k,hw] * fxs[b,hw,f] (both fp32) ----------------
__global__ void alpha2_k() {
    int bk = blockIdx.x;
    int b = bk >> 4;
    __shared__ float pl[4096];
    const float* pr = g_ws + OFF_PROBS + (size_t)bk * 4096;
    for (int i = threadIdx.x; i < 4096; i += 256) pl[i] = pr[i];
    __syncthreads();
    float acc[32];
    #pragma unroll
    for (int f = 0; f < 32; ++f) acc[f] = 0.f;
    for (int i = threadIdx.x; i < 4096; i += 256) {
        float pv = pl[i];
        const float* fp = g_ws + OFF_FXS + (size_t)(b * 4096 + i) * 32;
        #pragma unroll
        for (int f = 0; f < 32; ++f) acc[f] = fmaf(pv, fp[f], acc[f]);
    }
    __shared__ float sw[4][32];
    int lane = threadIdx.x & 63, wid = threadIdx.x >> 6;
    #pragma unroll
    for (int f = 0; f < 32; ++f)
        for (int off = 32; off; off >>= 1) acc[f] += __shfl_down(acc[f], off, 64);
    if (lane == 0) {
        #pragma unroll
        for (int f = 0; f < 32; ++f) sw[wid][f] = acc[f];
    }
    __syncthreads();
    if (threadIdx.x < 32)
        g_ws[OFF_ALPHA + bk * 32 + threadIdx.x] =
            sw[0][threadIdx.x] + sw[1][threadIdx.x] + sw[2][threadIdx.x] + sw[3][threadIdx.x];
}

// ---------------- heat -> E NHWC bf16 ch[0..16), + hsum ----------------
__global__ void heat2_k() {
    int bk = blockIdx.x;
    int b = bk >> 4, k = bk & 15;
    float m0 = g_ws[OFF_MU + bk * 2], m1 = g_ws[OFF_MU + bk * 2 + 1];
    float L00 = g_ws[OFF_LINV + bk * 4 + 0], L10 = g_ws[OFF_LINV + bk * 4 + 2],
          L11 = g_ws[OFF_LINV + bk * 4 + 3];
    __hip_bfloat16* E = (__hip_bfloat16*)g_ws + BA_E;
    float s = 0.f;
    for (int i = threadIdx.x; i < 4096; i += 256) {
        float d0 = -1.0f + (i >> 6) * (2.0f / 63.0f) - m0;
        float d1 = -1.0f + (i & 63) * (2.0f / 63.0f) - m1;
        float p0 = d0 * L00 + d1 * L10;
        float p1 = d1 * L11;
        float h = 1.0f / (1.0f + p0 * p0 + p1 * p1);
        E[(size_t)(b * 4096 + i) * 64 + k] = __float2bfloat16(h);
        s += h;
    }
    s = block_sum(s);
    if (threadIdx.x == 0) g_ws[OFF_HSUM + bk] = s;
}

// ---------------- fmap -> E ch[16..48), zero ch[48..64) ----------------
__global__ void fmap2_k() {
    int tile = blockIdx.x & 15, b = blockIdx.x >> 4;
    __shared__ float coef[16][32];
    for (int i = threadIdx.x; i < 512; i += 256) {
        int k = i >> 5, f = i & 31;
        coef[k][f] = g_ws[OFF_ALPHA + (b * 16 + k) * 32 + f] /
                     (g_ws[OFF_HSUM + b * 16 + k] + EPS);
    }
    __syncthreads();
    int pix = tile * 256 + threadIdx.x;
    __hip_bfloat16* E = (__hip_bfloat16*)g_ws + BA_E + (size_t)(b * 4096 + pix) * 64;
    float h[16];
    #pragma unroll
    for (int k = 0; k < 16; ++k) h[k] = __bfloat162float(E[k]);
    #pragma unroll
    for (int f = 0; f < 32; ++f) {
        float a = 0.f;
        #pragma unroll
        for (int k = 0; k < 16; ++k) a = fmaf(h[k], coef[k][f], a);
        E[16 + f] = __float2bfloat16(a);
    }
    #pragma unroll
    for (int z = 48; z < 64; ++z) E[z] = __float2bfloat16(0.f);
}

// ---------------- final conv(32->3) + sigmoid -> out, fused rec-loss; NHWC bf16 in ----------------
__global__ void __launch_bounds__(256)
conv_sign_k(const void* __restrict__ ximg, void* __restrict__ outp) {
    int bf = g_isbf16;
    int tile = blockIdx.x & 63, b = blockIdx.x >> 6;
    int pix = tile * 256 + threadIdx.x;
    int y = pix >> 7, x = pix & 127;
    const short* D2 = (const short*)((const __hip_bfloat16*)g_ws + BA_D2 + (size_t)b * 16384 * 32);
    float acc[3];
    #pragma unroll
    for (int o = 0; o < 3; ++o) acc[o] = g_wt[WT_DB3 + o];
    #pragma unroll
    for (int t = 0; t < 9; ++t) {
        int dy = t / 3 - 1, dx = t % 3 - 1;
        int yy = y + dy, xx = x + dx;
        if (yy < 0 || yy > 127 || xx < 0 || xx > 127) continue;
        const short* sp = D2 + (size_t)(yy * 128 + xx) * 32;
        #pragma unroll
        for (int c = 0; c < 4; ++c) {
            bf8v v = *(const bf8v*)(sp + c * 8);
            #pragma unroll
            for (int j = 0; j < 8; ++j) {
                float av = cvtbf(v[j]);
                int k = c * 8 + j;
                acc[0] = fmaf(av, g_wt[WT_W3P + (t * 3 + 0) * 32 + k], acc[0]);
                acc[1] = fmaf(av, g_wt[WT_W3P + (t * 3 + 1) * 32 + k], acc[1]);
                acc[2] = fmaf(av, g_wt[WT_W3P + (t * 3 + 2) * 32 + k], acc[2]);
            }
        }
    }
    float es = 0.f;
    #pragma unroll
    for (int o = 0; o < 3; ++o) {
        float v = 1.0f / (1.0f + __expf(-acc[o]));
        size_t oidx = ((size_t)b * 3 + o) * 16384 + pix;
        if (bf) ((__hip_bfloat16*)outp)[oidx] = __float2bfloat16(v);
        else    ((float*)outp)[oidx] = v;
        float e = ldin(ximg, oidx, bf) - v;
        es += e * e;
    }
    float s = block_sum(es);
    if (threadIdx.x == 0) atomicAdd(&g_ws[OFF_REC], s);
}

// ---------------- scalar loss ----------------
__global__ void loss_k(const void* __restrict__ coord,
                       const void* __restrict__ vec,
                       void* __restrict__ outp) {
    int bf = g_isbf16;
    const float* mu = g_ws + OFF_MU;
    const float* linv = g_ws + OFF_LINV;
    const float* mu_a = g_ws + OFF_MUA;
    const float* linv_a = g_ws + OFF_LINVA;
    float s1 = 0, s2 = 0, s3 = 0;
    for (int i = threadIdx.x; i < 1024; i += 256) {
        float d = mu[i] - mu_a[i];
        s1 += d * d;
        float t = ldin(coord, i, bf) + ldin(vec, i, bf);
        float d3 = mu_a[i] - t;
        s3 += d3 * d3;
    }
    for (int i = threadIdx.x; i < 2048; i += 256) {
        float d = linv[i] - linv_a[i];
        s2 += d * d;
    }
    s1 = block_sum(s1);
    s2 = block_sum(s2);
    s3 = block_sum(s3);
    if (threadIdx.x == 0) {
        float loss = g_ws[OFF_REC] / 1572864.0f + s1 / 1024.0f + 0.01f * (s2 / 2048.0f)
                   + s3 / 1024.0f;
        if (bf) ((__hip_bfloat16*)outp)[1572864] = __float2bfloat16(loss);
        else    ((float*)outp)[1572864] = loss;
    }
}

extern "C" void kernel_launch(void* const* d_in, const int* in_sizes, int n_in,
                              void* d_out, int out_size, void* d_ws, size_t ws_size,
                              hipStream_t stream) {
    const void* x     = d_in[0];
    const void* x_st  = d_in[1];
    const void* x_at  = d_in[2];
    const void* coord = d_in[3];
    const void* vec   = d_in[4];

    dim3 blk(256);

    detect_k<<<1, 64, 0, stream>>>(x);
    wpack_k<<<64, blk, 0, stream>>>(
        d_in[5],  d_in[6],  d_in[7],  d_in[8],
        d_in[9],  d_in[10], d_in[11], d_in[12],
        d_in[13], d_in[14], d_in[15], d_in[16],
        d_in[17], d_in[18], d_in[19], d_in[20]);

    // ---- encoder (B=64 batched, NHWC bf16): conv1 -> XA; conv2(MFMA) -> X2; parts(MFMA, fp32) ----
    conv_s2n_k<<<64 * 4 * 16, blk, 0, stream>>>(x_at, x_st);
    conv_mf_k<64, 2, 0, 1><<<2048, blk, 0, stream>>>(BA_XA, P_WP2, WT_ESB2, BA_X2);
    conv_mf_k<16, 1, 1, 0><<<1024, blk, 0, stream>>>(BA_X2, P_WPP, WT_ESBP, (size_t)OFF_PARTSF);
    sm_mom3_k<<<1024, blk, 0, stream>>>();

    // ---- e_alpha on app half -> FXS fp32; alpha ----
    conv_mf_k<64, 2, 0, 1><<<1024, blk, 0, stream>>>(BA_X2 + (size_t)32 * 4096 * 64, P_WPA1, WT_EAB1, BA_EA1);
    conv_mf_k<32, 1, 1, 0><<<1024, blk, 0, stream>>>(BA_EA1, P_WPA2, WT_EAB2, (size_t)OFF_FXS);
    alpha2_k<<<512, blk, 0, stream>>>();

    // ---- encoding E (NHWC bf16, 48+16pad): heat + fmap ----
    heat2_k<<<512, blk, 0, stream>>>();
    fmap2_k<<<512, blk, 0, stream>>>();

    // ---- decoder: dw1(MFMA) -> D1; upconv(MFMA) -> D2; sig conv -> out ----
    conv_mf_k<64, 2, 0, 1><<<1024, blk, 0, stream>>>(BA_E, P_WPD1, WT_DB1, BA_D1);
    conv_upmf_k<<<2048, blk, 0, stream>>>(BA_D1, P_WPD2, WT_DB2, BA_D2);
    conv_sign_k<<<32 * 64, blk, 0, stream>>>(x, d_out);

    // ---- loss ----
    loss_k<<<1, blk, 0, stream>>>(coord, vec, d_out);
}

// Round 18
// 498.500 us; speedup vs baseline: 1.3084x; 1.3084x over previous
//
#include <hip/hip_runtime.h>
#include <hip/hip_bf16.h>

#define EPS 1e-6f
#define SCAL 5.0f

typedef __attribute__((ext_vector_type(8))) short bf8v;   // 8 bf16 (4 VGPRs)
typedef __attribute__((ext_vector_type(4))) float f32x4;  // MFMA acc

// ---- workspace (float units) ----
#define OFF_MU     0
#define OFF_LINV   1024
#define OFF_MUA    3072
#define OFF_LINVA  4096
#define OFF_HSUM   6144
#define OFF_ALPHA  6656
#define OFF_REC    23040
#define OFF_R1     32768
#define OFF_R2     (OFF_R1 + 8388608)
#define OFF_R3     (OFF_R2 + 8388608)
#define WS_TOTAL   (OFF_R3 + 16777216)

// NHWC bf16 tensors (offsets in bf16 elements) and fp32 tensors (float offsets)
#define BA_XA   ((size_t)2 * OFF_R3)            // conv1 out [64,4096,64]
#define BA_X2   ((size_t)2 * OFF_R1)            // conv2 out [64,4096,64]
#define OFF_PARTSF OFF_R2                        // parts logits fp32 [64,4096,16]
#define OFF_PROBS  (OFF_R2 + 4194304)            // app probs fp32 [32,16,4096]
#define BA_EA1  ((size_t)2 * OFF_R3)            // ea1 out [32,4096,64]
#define OFF_FXS (OFF_R3 + 4194304)              // f_xs fp32 [32,4096,32]
#define BA_E    ((size_t)2 * OFF_R2)            // encoding [32,4096,64] (48 real + 16 pad)
#define BA_D1   ((size_t)2 * OFF_R1)            // dw1 out [32,4096,64]
#define BA_D2   ((size_t)2 * OFF_R3)            // upconv out [32,16384,32]

// g_wt fp32 layout
#define WT_ESW1 0
#define WT_ESB1 1728
#define WT_ESB2 1792
#define WT_ESBP 1856
#define WT_EAB1 1872
#define WT_EAB2 1936
#define WT_DB1  1968
#define WT_DB2  2032
#define WT_W3P  2064
#define WT_DB3  2928
// g_wp bf16 packed weights [tap][oc][ic]
#define P_WP2  0
#define P_WPP  36864
#define P_WPA1 46080
#define P_WPA2 82944
#define P_WPD1 101376
#define P_WPD2 138240

__device__ __attribute__((aligned(16))) float g_ws[WS_TOTAL];
__device__ __attribute__((aligned(16))) float g_wt[3072];
__device__ __attribute__((aligned(16))) __hip_bfloat16 g_wp[156672];
__device__ int g_isbf16;

__device__ __forceinline__ float selz(bool c, float v) { return c ? v : 0.f; }
__device__ __forceinline__ float cvtbf(short s) {
    return __uint_as_float(((unsigned int)(unsigned short)s) << 16);
}
// runtime-dtype external load (adaptive — fixed-dtype builds NaN'd in rounds 1/2/7)
__device__ __forceinline__ float ldin(const void* p, size_t i, int bf) {
    return bf ? __bfloat162float(((const __hip_bfloat16*)p)[i])
              : ((const float*)p)[i];
}

// ---------------- block reductions (blockDim.x == 256) ----------------
__device__ __forceinline__ float block_sum(float v) {
    __shared__ float sb[8];
    for (int off = 32; off; off >>= 1) v += __shfl_down(v, off, 64);
    int lane = threadIdx.x & 63, wid = threadIdx.x >> 6;
    __syncthreads();
    if (lane == 0) sb[wid] = v;
    __syncthreads();
    float r = 0.f;
    for (int i = 0; i < 4; ++i) r += sb[i];
    return r;
}
__device__ __forceinline__ float block_max(float v) {
    __shared__ float sb[8];
    for (int off = 32; off; off >>= 1) v = fmaxf(v, __shfl_down(v, off, 64));
    int lane = threadIdx.x & 63, wid = threadIdx.x >> 6;
    __syncthreads();
    if (lane == 0) sb[wid] = v;
    __syncthreads();
    float r = -1e30f;
    for (int i = 0; i < 4; ++i) r = fmaxf(r, sb[i]);
    return r;
}

// ---------------- dtype probe + init ----------------
__global__ void detect_k(const void* x) {
    const __hip_bfloat16* p = (const __hip_bfloat16*)x;
    int lane = threadIdx.x & 63;
    float v = 0.f;
    for (int i = lane; i < 256; i += 64) {
        float a = fabsf(__bfloat162float(p[i]));
        if (!(a <= 2.0f)) v = 1.f;
    }
    for (int off = 32; off; off >>= 1) v += __shfl_down(v, off, 64);
    if (lane == 0) {
        g_isbf16 = (v == 0.f) ? 1 : 0;
        g_ws[OFF_REC] = 0.f;
    }
}

// ---------------- weight pack: ext dtype -> g_wt fp32 + g_wp bf16 [t][n][k] ----------------
__global__ void wpack_k(const void* esw1, const void* esb1, const void* esw2, const void* esb2,
                        const void* eswp, const void* esbp, const void* eaw1, const void* eab1,
                        const void* eaw2, const void* eab2, const void* dw1, const void* db1,
                        const void* dw2, const void* db2, const void* dw3, const void* db3) {
    int bf = g_isbf16;
    int gid0 = blockIdx.x * 256 + threadIdx.x, stride = gridDim.x * 256;
    for (int g = gid0; g < 1728; g += stride) g_wt[WT_ESW1 + g] = ldin(esw1, g, bf);
    for (int g = gid0; g < 64; g += stride) g_wt[WT_ESB1 + g] = ldin(esb1, g, bf);
    for (int g = gid0; g < 64; g += stride) g_wt[WT_ESB2 + g] = ldin(esb2, g, bf);
    for (int g = gid0; g < 16; g += stride) g_wt[WT_ESBP + g] = ldin(esbp, g, bf);
    for (int g = gid0; g < 64; g += stride) g_wt[WT_EAB1 + g] = ldin(eab1, g, bf);
    for (int g = gid0; g < 32; g += stride) g_wt[WT_EAB2 + g] = ldin(eab2, g, bf);
    for (int g = gid0; g < 64; g += stride) g_wt[WT_DB1 + g] = ldin(db1, g, bf);
    for (int g = gid0; g < 32; g += stride) g_wt[WT_DB2 + g] = ldin(db2, g, bf);
    for (int g = gid0; g < 3; g += stride) g_wt[WT_DB3 + g] = ldin(db3, g, bf);
    for (int g = gid0; g < 864; g += stride) {              // w3p[t][o][k]
        int t = g / 96, o = (g / 32) % 3, k = g & 31;
        g_wt[WT_W3P + g] = ldin(dw3, (size_t)(o * 32 + k) * 9 + t, bf);
    }
    for (int g = gid0; g < 36864; g += stride) {            // wp2[t][n][k] from es_w2[n][k][t]
        int t = g >> 12, n = (g >> 6) & 63, k = g & 63;
        g_wp[P_WP2 + g] = __float2bfloat16(ldin(esw2, (size_t)(n * 64 + k) * 9 + t, bf));
    }
    for (int g = gid0; g < 9216; g += stride) {             // wpp[t][n<16][k]
        int t = g >> 10, n = (g >> 6) & 15, k = g & 63;
        g_wp[P_WPP + g] = __float2bfloat16(ldin(eswp, (size_t)(n * 64 + k) * 9 + t, bf));
    }
    for (int g = gid0; g < 36864; g += stride) {            // wpa1
        int t = g >> 12, n = (g >> 6) & 63, k = g & 63;
        g_wp[P_WPA1 + g] = __float2bfloat16(ldin(eaw1, (size_t)(n * 64 + k) * 9 + t, bf));
    }
    for (int g = gid0; g < 18432; g += stride) {            // wpa2[t][n<32][k]
        int t = g >> 11, n = (g >> 6) & 31, k = g & 63;
        g_wp[P_WPA2 + g] = __float2bfloat16(ldin(eaw2, (size_t)(n * 64 + k) * 9 + t, bf));
    }
    for (int g = gid0; g < 36864; g += stride) {            // wpd1: K=48 zero-padded to 64
        int t = g >> 12, n = (g >> 6) & 63, k = g & 63;
        float v = (k < 48) ? ldin(dw1, (size_t)(n * 48 + k) * 9 + t, bf) : 0.f;
        g_wp[P_WPD1 + g] = __float2bfloat16(v);
    }
    for (int g = gid0; g < 18432; g += stride) {            // wpd2[t][n<32][k]
        int t = g >> 11, n = (g >> 6) & 31, k = g & 63;
        g_wp[P_WPD2 + g] = __float2bfloat16(ldin(dw2, (size_t)(n * 64 + k) * 9 + t, bf));
    }
}

// ---------------- conv1 both streams: stride-2 -> NHWC bf16 [64,4096,64], relu ----
__global__ void __launch_bounds__(256)
conv_s2n_k(const void* __restrict__ inA, const void* __restrict__ inB) {
    int bf = g_isbf16;
    int tile = blockIdx.x & 15;
    int gb = blockIdx.x >> 4;
    int g = gb & 3, b = gb >> 2;
    const void* in = (b < 32) ? inA : inB;
    int bb = b & 31;
    int pix = tile * 256 + threadIdx.x;
    int y = pix >> 6, x = pix & 63;
    size_t inb = (size_t)bb * 3 * 16384;
    const float* W = g_wt + WT_ESW1 + (size_t)(g * 16) * 27;
    float acc[16];
    #pragma unroll
    for (int o = 0; o < 16; ++o) acc[o] = g_wt[WT_ESB1 + g * 16 + o];
    int iy0 = 2 * y, ix0 = 2 * x;
    bool my2 = (iy0 + 2 < 128), mx2 = (ix0 + 2 < 128);
    int iy2 = my2 ? iy0 + 2 : 127, ix2 = mx2 ? ix0 + 2 : 127;
    for (int ic = 0; ic < 3; ++ic) {
        size_t pb = inb + ic * 16384;
        float t[9];
        t[0] = ldin(in, pb + iy0 * 128 + ix0, bf);
        t[1] = ldin(in, pb + iy0 * 128 + ix0 + 1, bf);
        t[2] = selz(mx2, ldin(in, pb + iy0 * 128 + ix2, bf));
        t[3] = ldin(in, pb + (iy0 + 1) * 128 + ix0, bf);
        t[4] = ldin(in, pb + (iy0 + 1) * 128 + ix0 + 1, bf);
        t[5] = selz(mx2, ldin(in, pb + (iy0 + 1) * 128 + ix2, bf));
        t[6] = selz(my2, ldin(in, pb + iy2 * 128 + ix0, bf));
        t[7] = selz(my2, ldin(in, pb + iy2 * 128 + ix0 + 1, bf));
        t[8] = selz(my2 && mx2, ldin(in, pb + iy2 * 128 + ix2, bf));
        #pragma unroll
        for (int o = 0; o < 16; ++o) {
            const float* wr = W + (o * 3 + ic) * 9;
            float a = acc[o];
            #pragma unroll
            for (int j = 0; j < 9; ++j) a = fmaf(t[j], wr[j], a);
            acc[o] = a;
        }
    }
    __hip_bfloat16* out = (__hip_bfloat16*)g_ws + BA_XA + ((size_t)b * 4096 + pix) * 64 + g * 16;
    #pragma unroll
    for (int o = 0; o < 16; ++o) out[o] = __float2bfloat16(fmaxf(acc[o], 0.f));
}

// ---------------- LDS-staged MFMA 3x3 conv on 64x64 NHWC (Cin=64) ----------------
// Block = 4 waves = 4 consecutive rows of one batch. LDS tile: 6 halo rows x 66 px
// (1 zero-pad px each side) x 64 ch, 16B chunks swizzled (slot = j ^ (P&7)).
// Removes the 16-line scatter of global A-loads (round-17 diagnosis) and all
// boundary branches. A[m=lane&15][k=quad*8+j]; B[k][n=lane&15]; C col=l15 row=quad*4+r.
template<int TOTN, int NS, int OUTF32, int RELU>
__global__ void __launch_bounds__(256) __attribute__((amdgpu_waves_per_eu(2, 4)))
conv_mfl_k(size_t in_off, int wp_off, int bias_off, size_t out_off) {
    __shared__ __hip_bfloat16 sA[6 * 66 * 64];   // 50688 B -> 3 blocks/CU
    int wid = threadIdx.x >> 6, lane = threadIdx.x & 63;
    int l15 = lane & 15, quad = lane >> 4;
    int b = blockIdx.x >> 4, y0 = (blockIdx.x & 15) * 4;
    const __hip_bfloat16* inb = (const __hip_bfloat16*)g_ws + in_off + (size_t)b * 4096 * 64;
    // ---- stage 6 rows x 64 px x 8 chunks (16B each); coalesced dwordx4 ----
    for (int g = threadIdx.x; g < 3072; g += 256) {
        int r = g >> 9;                 // 0..5
        int rem = g & 511;
        int px = rem >> 3, j = rem & 7;
        int yy = y0 - 1 + r;
        int P = px + 1;
        bf8v v = (bf8v){0, 0, 0, 0, 0, 0, 0, 0};
        if (yy >= 0 && yy <= 63)
            v = *(const bf8v*)(inb + ((size_t)(yy * 64 + px) * 64 + j * 8));
        *(bf8v*)(sA + ((r * 66 + P) * 64 + ((j ^ (P & 7)) * 8))) = v;
    }
    if (threadIdx.x < 96) {             // zero pads P=0 and P=65
        int g = threadIdx.x;
        int r = g / 16, rem = g % 16, side = rem >> 3, j = rem & 7;
        int P = side ? 65 : 0;
        *(bf8v*)(sA + ((r * 66 + P) * 64 + ((j ^ (P & 7)) * 8))) = (bf8v){0, 0, 0, 0, 0, 0, 0, 0};
    }
    __syncthreads();
    int y = y0 + wid;
    f32x4 acc[4][NS];
    #pragma unroll
    for (int ms = 0; ms < 4; ++ms)
        #pragma unroll
        for (int ns = 0; ns < NS; ++ns) acc[ms][ns] = (f32x4){0.f, 0.f, 0.f, 0.f};
    #pragma unroll
    for (int t = 0; t < 9; ++t) {
        int dy = t / 3 - 1, dx = t % 3 - 1;
        int r = wid + 1 + dy;           // 0..5, always valid (halo pre-zeroed)
        #pragma unroll
        for (int c = 0; c < 2; ++c) {
            int j = c * 4 + quad;
            bf8v a[4];
            #pragma unroll
            for (int ms = 0; ms < 4; ++ms) {
                int P = ms * 16 + l15 + dx + 1;   // 0..65, always valid
                a[ms] = *(const bf8v*)(sA + ((r * 66 + P) * 64 + ((j ^ (P & 7)) * 8)));
            }
            #pragma unroll
            for (int ns = 0; ns < NS; ++ns) {
                bf8v bv = *(const bf8v*)(g_wp + wp_off +
                          ((size_t)(t * TOTN + ns * 16 + l15) * 64 + c * 32 + quad * 8));
                #pragma unroll
                for (int ms = 0; ms < 4; ++ms)
                    acc[ms][ns] = __builtin_amdgcn_mfma_f32_16x16x32_bf16(a[ms], bv, acc[ms][ns], 0, 0, 0);
            }
        }
    }
    #pragma unroll
    for (int ns = 0; ns < NS; ++ns) {
        float bias = g_wt[bias_off + ns * 16 + l15];
        #pragma unroll
        for (int ms = 0; ms < 4; ++ms) {
            #pragma unroll
            for (int r = 0; r < 4; ++r) {
                int pix = ms * 16 + quad * 4 + r;
                float v = acc[ms][ns][r] + bias;
                if (RELU) v = fmaxf(v, 0.f);
                size_t o = out_off + ((size_t)(b * 4096 + y * 64 + pix)) * TOTN + ns * 16 + l15;
                if (OUTF32) g_ws[o] = v;
                else ((__hip_bfloat16*)g_ws)[o] = __float2bfloat16(v);
            }
        }
    }
}

// ---------------- MFMA decoder conv2 + 2x nearest upsample (round-16 version) ----
__global__ void __launch_bounds__(256) __attribute__((amdgpu_waves_per_eu(2, 4)))
conv_upmf_k(size_t in_off, int wp_off, int bias_off, size_t out_off) {
    int wid = threadIdx.x >> 6, lane = threadIdx.x & 63;
    int l15 = lane & 15, quad = lane >> 4;
    int row = blockIdx.x * 4 + wid;
    int b = row >> 7, y = row & 127;
    const __hip_bfloat16* inb = (const __hip_bfloat16*)g_ws + in_off + (size_t)b * 4096 * 64;
    f32x4 acc[8][2];
    #pragma unroll
    for (int ms = 0; ms < 8; ++ms)
        #pragma unroll
        for (int ns = 0; ns < 2; ++ns) acc[ms][ns] = (f32x4){0.f, 0.f, 0.f, 0.f};
    #pragma unroll
    for (int t = 0; t < 9; ++t) {
        int dy = t / 3 - 1, dx = t % 3 - 1;
        int yy = y + dy;
        if (yy < 0 || yy > 127) continue;
        int yi = yy >> 1;
        #pragma unroll
        for (int c = 0; c < 2; ++c) {
            bf8v a[8];
            #pragma unroll
            for (int ms = 0; ms < 8; ++ms) {
                int xx = ms * 16 + l15 + dx;
                bool v = (xx >= 0 && xx < 128);
                int xi = (v ? xx : 0) >> 1;
                bf8v av = *(const bf8v*)(inb + ((size_t)(yi * 64 + xi) * 64 + c * 32 + quad * 8));
                if (!v) av = (bf8v){0, 0, 0, 0, 0, 0, 0, 0};
                a[ms] = av;
            }
            #pragma unroll
            for (int ns = 0; ns < 2; ++ns) {
                bf8v bv = *(const bf8v*)(g_wp + wp_off +
                          ((size_t)(t * 32 + ns * 16 + l15) * 64 + c * 32 + quad * 8));
                #pragma unroll
                for (int ms = 0; ms < 8; ++ms)
                    acc[ms][ns] = __builtin_amdgcn_mfma_f32_16x16x32_bf16(a[ms], bv, acc[ms][ns], 0, 0, 0);
            }
        }
    }
    #pragma unroll
    for (int ns = 0; ns < 2; ++ns) {
        float bias = g_wt[bias_off + ns * 16 + l15];
        #pragma unroll
        for (int ms = 0; ms < 8; ++ms) {
            #pragma unroll
            for (int r = 0; r < 4; ++r) {
                int pix = ms * 16 + quad * 4 + r;
                float v = fmaxf(acc[ms][ns][r] + bias, 0.f);
                size_t o = out_off + ((size_t)(b * 16384 + y * 128 + pix)) * 32 + ns * 16 + l15;
                ((__hip_bfloat16*)g_ws)[o] = __float2bfloat16(v);
            }
        }
    }
}

// ---------------- fused softmax+moments: parts logits fp32 NHWC [64,4096,16] ----------------
__global__ void sm_mom3_k() {
    int bk = blockIdx.x;
    int b = bk >> 4, k = bk & 15;
    int app = (b >= 32);
    const float* P = g_ws + OFF_PARTSF + (size_t)b * 4096 * 16 + k;
    float r[16];
    #pragma unroll
    for (int j = 0; j < 16; ++j) r[j] = P[(size_t)(threadIdx.x + j * 256) * 16];
    float m = r[0];
    #pragma unroll
    for (int j = 1; j < 16; ++j) m = fmaxf(m, r[j]);
    m = block_max(m);
    float s = 0.f;
    #pragma unroll
    for (int j = 0; j < 16; ++j) { r[j] = __expf(r[j] - m); s += r[j]; }
    s = block_sum(s);
    float inv = 1.0f / s;
    float sy = 0, sx = 0, syy = 0, sxy = 0, sxx = 0;
    #pragma unroll
    for (int j = 0; j < 16; ++j) {
        float pv = r[j] * inv;
        int i = threadIdx.x + j * 256;
        if (app) g_ws[OFF_PROBS + ((size_t)(b - 32) * 16 + k) * 4096 + i] = pv;
        float gy = -1.0f + (i >> 6) * (2.0f / 63.0f);
        float gx = -1.0f + (i & 63) * (2.0f / 63.0f);
        sy += pv * gy; sx += pv * gx;
        syy += pv * gy * gy; sxy += pv * gy * gx; sxx += pv * gx * gx;
    }
    sy = block_sum(sy); sx = block_sum(sx);
    syy = block_sum(syy); sxy = block_sum(sxy); sxx = block_sum(sxx);
    if (threadIdx.x == 0) {
        float c00 = syy - sy * sy, c01 = sxy - sy * sx, c11 = sxx - sx * sx;
        float a = sqrtf(fmaxf(c00 + EPS, 1e-12f));
        float bb = c01 / (a + EPS);
        float cc = sqrtf(fmaxf(c11 - bb * bb, 0.f) + EPS);
        float det = a * cc;
        float sc = SCAL / (det + EPS);
        int idx = app ? ((b - 32) * 16 + k) : (b * 16 + k);
        int mu_off = app ? OFF_MUA : OFF_MU;
        int linv_off = app ? OFF_LINVA : OFF_LINV;
        g_ws[mu_off + idx * 2 + 0] = sy;
        g_ws[mu_off + idx * 2 + 1] = sx;
        g_ws[linv_off + idx * 4 + 0] = cc * sc;
        g_ws[linv_off + idx * 4 + 1] = 0.f;
        g_ws[linv_off + idx * 4 + 2] = -bb * sc;
        g_ws[linv_off + idx * 4 + 3] = a * sc;
    }
}

// ---------------- alpha[b,k,f] = sum_hw probs[b,k,hw] * fxs[b,hw,f] (both fp32) ----------------
__global__ void alpha2_k() {
    int bk = blockIdx.x;
    int b = bk >> 4;
    __shared__ float pl[4096];
    const float* pr = g_ws + OFF_PROBS + (size_t)bk * 4096;
    for (int i = threadIdx.x; i < 4096; i += 256) pl[i] = pr[i];
    __syncthreads();
    float acc[32];
    #pragma unroll
    for (int f = 0; f < 32; ++f) acc[f] = 0.f;
    for (int i = threadIdx.x; i < 4096; i += 256) {
        float pv = pl[i];
        const float* fp = g_ws + OFF_FXS + (size_t)(b * 4096 + i) * 32;
        #pragma unroll
        for (int f = 0; f < 32; ++f) acc[f] = fmaf(pv, fp[f], acc[f]);
    }
    __shared__ float sw[4][32];
    int lane = threadIdx.x & 63, wid = threadIdx.x >> 6;
    #pragma unroll
    for (int f = 0; f < 32; ++f)
        for (int off = 32; off; off >>= 1) acc[f] += __shfl_down(acc[f], off, 64);
    if (lane == 0) {
        #pragma unroll
        for (int f = 0; f < 32; ++f) sw[wid][f] = acc[f];
    }
    __syncthreads();
    if (threadIdx.x < 32)
        g_ws[OFF_ALPHA + bk * 32 + threadIdx.x] =
            sw[0][threadIdx.x] + sw[1][threadIdx.x] + sw[2][threadIdx.x] + sw[3][threadIdx.x];
}

// ---------------- heat -> E NHWC bf16 ch[0..16), + hsum ----------------
__global__ void heat2_k() {
    int bk = blockIdx.x;
    int b = bk >> 4, k = bk & 15;
    float m0 = g_ws[OFF_MU + bk * 2], m1 = g_ws[OFF_MU + bk * 2 + 1];
    float L00 = g_ws[OFF_LINV + bk * 4 + 0], L10 = g_ws[OFF_LINV + bk * 4 + 2],
          L11 = g_ws[OFF_LINV + bk * 4 + 3];
    __hip_bfloat16* E = (__hip_bfloat16*)g_ws + BA_E;
    float s = 0.f;
    for (int i = threadIdx.x; i < 4096; i += 256) {
        float d0 = -1.0f + (i >> 6) * (2.0f / 63.0f) - m0;
        float d1 = -1.0f + (i & 63) * (2.0f / 63.0f) - m1;
        float p0 = d0 * L00 + d1 * L10;
        float p1 = d1 * L11;
        float h = 1.0f / (1.0f + p0 * p0 + p1 * p1);
        E[(size_t)(b * 4096 + i) * 64 + k] = __float2bfloat16(h);
        s += h;
    }
    s = block_sum(s);
    if (threadIdx.x == 0) g_ws[OFF_HSUM + bk] = s;
}

// ---------------- fmap -> E ch[16..48), zero ch[48..64) ----------------
__global__ void fmap2_k() {
    int tile = blockIdx.x & 15, b = blockIdx.x >> 4;
    __shared__ float coef[16][32];
    for (int i = threadIdx.x; i < 512; i += 256) {
        int k = i >> 5, f = i & 31;
        coef[k][f] = g_ws[OFF_ALPHA + (b * 16 + k) * 32 + f] /
                     (g_ws[OFF_HSUM + b * 16 + k] + EPS);
    }
    __syncthreads();
    int pix = tile * 256 + threadIdx.x;
    __hip_bfloat16* E = (__hip_bfloat16*)g_ws + BA_E + (size_t)(b * 4096 + pix) * 64;
    float h[16];
    #pragma unroll
    for (int k = 0; k < 16; ++k) h[k] = __bfloat162float(E[k]);
    #pragma unroll
    for (int f = 0; f < 32; ++f) {
        float a = 0.f;
        #pragma unroll
        for (int k = 0; k < 16; ++k) a = fmaf(h[k], coef[k][f], a);
        E[16 + f] = __float2bfloat16(a);
    }
    #pragma unroll
    for (int z = 48; z < 64; ++z) E[z] = __float2bfloat16(0.f);
}

// ---------------- final conv(32->3) + sigmoid -> out, fused rec-loss; NHWC bf16 in ----------------
__global__ void __launch_bounds__(256)
conv_sign_k(const void* __restrict__ ximg, void* __restrict__ outp) {
    int bf = g_isbf16;
    int tile = blockIdx.x & 63, b = blockIdx.x >> 6;
    int pix = tile * 256 + threadIdx.x;
    int y = pix >> 7, x = pix & 127;
    const short* D2 = (const short*)((const __hip_bfloat16*)g_ws + BA_D2 + (size_t)b * 16384 * 32);
    float acc[3];
    #pragma unroll
    for (int o = 0; o < 3; ++o) acc[o] = g_wt[WT_DB3 + o];
    #pragma unroll
    for (int t = 0; t < 9; ++t) {
        int dy = t / 3 - 1, dx = t % 3 - 1;
        int yy = y + dy, xx = x + dx;
        if (yy < 0 || yy > 127 || xx < 0 || xx > 127) continue;
        const short* sp = D2 + (size_t)(yy * 128 + xx) * 32;
        #pragma unroll
        for (int c = 0; c < 4; ++c) {
            bf8v v = *(const bf8v*)(sp + c * 8);
            #pragma unroll
            for (int j = 0; j < 8; ++j) {
                float av = cvtbf(v[j]);
                int k = c * 8 + j;
                acc[0] = fmaf(av, g_wt[WT_W3P + (t * 3 + 0) * 32 + k], acc[0]);
                acc[1] = fmaf(av, g_wt[WT_W3P + (t * 3 + 1) * 32 + k], acc[1]);
                acc[2] = fmaf(av, g_wt[WT_W3P + (t * 3 + 2) * 32 + k], acc[2]);
            }
        }
    }
    float es = 0.f;
    #pragma unroll
    for (int o = 0; o < 3; ++o) {
        float v = 1.0f / (1.0f + __expf(-acc[o]));
        size_t oidx = ((size_t)b * 3 + o) * 16384 + pix;
        if (bf) ((__hip_bfloat16*)outp)[oidx] = __float2bfloat16(v);
        else    ((float*)outp)[oidx] = v;
        float e = ldin(ximg, oidx, bf) - v;
        es += e * e;
    }
    float s = block_sum(es);
    if (threadIdx.x == 0) atomicAdd(&g_ws[OFF_REC], s);
}

// ---------------- scalar loss ----------------
__global__ void loss_k(const void* __restrict__ coord,
                       const void* __restrict__ vec,
                       void* __restrict__ outp) {
    int bf = g_isbf16;
    const float* mu = g_ws + OFF_MU;
    const float* linv = g_ws + OFF_LINV;
    const float* mu_a = g_ws + OFF_MUA;
    const float* linv_a = g_ws + OFF_LINVA;
    float s1 = 0, s2 = 0, s3 = 0;
    for (int i = threadIdx.x; i < 1024; i += 256) {
        float d = mu[i] - mu_a[i];
        s1 += d * d;
        float t = ldin(coord, i, bf) + ldin(vec, i, bf);
        float d3 = mu_a[i] - t;
        s3 += d3 * d3;
    }
    for (int i = threadIdx.x; i < 2048; i += 256) {
        float d = linv[i] - linv_a[i];
        s2 += d * d;
    }
    s1 = block_sum(s1);
    s2 = block_sum(s2);
    s3 = block_sum(s3);
    if (threadIdx.x == 0) {
        float loss = g_ws[OFF_REC] / 1572864.0f + s1 / 1024.0f + 0.01f * (s2 / 2048.0f)
                   + s3 / 1024.0f;
        if (bf) ((__hip_bfloat16*)outp)[1572864] = __float2bfloat16(loss);
        else    ((float*)outp)[1572864] = loss;
    }
}

extern "C" void kernel_launch(void* const* d_in, const int* in_sizes, int n_in,
                              void* d_out, int out_size, void* d_ws, size_t ws_size,
                              hipStream_t stream) {
    const void* x     = d_in[0];
    const void* x_st  = d_in[1];
    const void* x_at  = d_in[2];
    const void* coord = d_in[3];
    const void* vec   = d_in[4];

    dim3 blk(256);

    detect_k<<<1, 64, 0, stream>>>(x);
    wpack_k<<<64, blk, 0, stream>>>(
        d_in[5],  d_in[6],  d_in[7],  d_in[8],
        d_in[9],  d_in[10], d_in[11], d_in[12],
        d_in[13], d_in[14], d_in[15], d_in[16],
        d_in[17], d_in[18], d_in[19], d_in[20]);

    // ---- encoder (B=64 batched, NHWC bf16): conv1 -> XA; conv2(MFMA+LDS) -> X2; parts ----
    conv_s2n_k<<<64 * 4 * 16, blk, 0, stream>>>(x_at, x_st);
    conv_mfl_k<64, 4, 0, 1><<<1024, blk, 0, stream>>>(BA_XA, P_WP2, WT_ESB2, BA_X2);
    conv_mfl_k<16, 1, 1, 0><<<1024, blk, 0, stream>>>(BA_X2, P_WPP, WT_ESBP, (size_t)OFF_PARTSF);
    sm_mom3_k<<<1024, blk, 0, stream>>>();

    // ---- e_alpha on app half -> FXS fp32; alpha ----
    conv_mfl_k<64, 4, 0, 1><<<512, blk, 0, stream>>>(BA_X2 + (size_t)32 * 4096 * 64, P_WPA1, WT_EAB1, BA_EA1);
    conv_mfl_k<32, 2, 1, 0><<<512, blk, 0, stream>>>(BA_EA1, P_WPA2, WT_EAB2, (size_t)OFF_FXS);
    alpha2_k<<<512, blk, 0, stream>>>();

    // ---- encoding E (NHWC bf16, 48+16pad): heat + fmap ----
    heat2_k<<<512, blk, 0, stream>>>();
    fmap2_k<<<512, blk, 0, stream>>>();

    // ---- decoder: dw1(MFMA+LDS) -> D1; upconv(MFMA) -> D2; sig conv -> out ----
    conv_mfl_k<64, 4, 0, 1><<<512, blk, 0, stream>>>(BA_E, P_WPD1, WT_DB1, BA_D1);
    conv_upmf_k<<<1024, blk, 0, stream>>>(BA_D1, P_WPD2, WT_DB2, BA_D2);
    conv_sign_k<<<32 * 64, blk, 0, stream>>>(x, d_out);

    // ---- loss ----
    loss_k<<<1, blk, 0, stream>>>(coord, vec, d_out);
}

// Round 19
// 467.449 us; speedup vs baseline: 1.3953x; 1.0664x over previous
//
#include <hip/hip_runtime.h>
#include <hip/hip_bf16.h>

#define EPS 1e-6f
#define SCAL 5.0f

typedef __attribute__((ext_vector_type(8))) short bf8v;   // 8 bf16 (4 VGPRs)
typedef __attribute__((ext_vector_type(4))) float f32x4;  // MFMA acc

// ---- workspace (float units) ----
#define OFF_MU     0
#define OFF_LINV   1024
#define OFF_MUA    3072
#define OFF_LINVA  4096
#define OFF_HSUM   6144
#define OFF_ALPHA  6656
#define OFF_REC    23040
#define OFF_R1     32768
#define OFF_R2     (OFF_R1 + 8388608)
#define OFF_R3     (OFF_R2 + 8388608)
#define WS_TOTAL   (OFF_R3 + 16777216)

// NHWC bf16 tensors (offsets in bf16 elements) and fp32 tensors (float offsets)
#define BA_XA   ((size_t)2 * OFF_R3)            // conv1 out [64,4096,64]
#define BA_X2   ((size_t)2 * OFF_R1)            // conv2 out [64,4096,64]
#define OFF_PARTSF OFF_R2                        // parts logits fp32 [64,4096,16]
#define OFF_PROBS  (OFF_R2 + 4194304)            // app probs fp32 [32,16,4096]
#define BA_EA1  ((size_t)2 * OFF_R3)            // ea1 out [32,4096,64]
#define OFF_FXS (OFF_R3 + 4194304)              // f_xs fp32 [32,4096,32]
#define BA_E    ((size_t)2 * OFF_R2)            // encoding [32,4096,64] (48 real + 16 pad)
#define BA_D1   ((size_t)2 * OFF_R1)            // dw1 out [32,4096,64]
#define BA_D2   ((size_t)2 * OFF_R3)            // upconv out [32,16384,32]

// g_wt fp32 layout
#define WT_ESW1 0
#define WT_ESB1 1728
#define WT_ESB2 1792
#define WT_ESBP 1856
#define WT_EAB1 1872
#define WT_EAB2 1936
#define WT_DB1  1968
#define WT_DB2  2032
#define WT_W3P  2064
#define WT_DB3  2928
// g_wp bf16 packed weights [tap][oc][ic]
#define P_WP2  0
#define P_WPP  36864
#define P_WPA1 46080
#define P_WPA2 82944
#define P_WPD1 101376
#define P_WPD2 138240

__device__ __attribute__((aligned(16))) float g_ws[WS_TOTAL];
__device__ __attribute__((aligned(16))) float g_wt[3072];
__device__ __attribute__((aligned(16))) __hip_bfloat16 g_wp[156672];
__device__ int g_isbf16;

__device__ __forceinline__ float selz(bool c, float v) { return c ? v : 0.f; }
__device__ __forceinline__ float cvtbf(short s) {
    return __uint_as_float(((unsigned int)(unsigned short)s) << 16);
}
// runtime-dtype external load (adaptive — fixed-dtype builds NaN'd in rounds 1/2/7)
__device__ __forceinline__ float ldin(const void* p, size_t i, int bf) {
    return bf ? __bfloat162float(((const __hip_bfloat16*)p)[i])
              : ((const float*)p)[i];
}

// ---------------- block reductions (blockDim.x == 256) ----------------
__device__ __forceinline__ float block_sum(float v) {
    __shared__ float sb[8];
    for (int off = 32; off; off >>= 1) v += __shfl_down(v, off, 64);
    int lane = threadIdx.x & 63, wid = threadIdx.x >> 6;
    __syncthreads();
    if (lane == 0) sb[wid] = v;
    __syncthreads();
    float r = 0.f;
    for (int i = 0; i < 4; ++i) r += sb[i];
    return r;
}
__device__ __forceinline__ float block_max(float v) {
    __shared__ float sb[8];
    for (int off = 32; off; off >>= 1) v = fmaxf(v, __shfl_down(v, off, 64));
    int lane = threadIdx.x & 63, wid = threadIdx.x >> 6;
    __syncthreads();
    if (lane == 0) sb[wid] = v;
    __syncthreads();
    float r = -1e30f;
    for (int i = 0; i < 4; ++i) r = fmaxf(r, sb[i]);
    return r;
}

// ---------------- dtype probe + init ----------------
__global__ void detect_k(const void* x) {
    const __hip_bfloat16* p = (const __hip_bfloat16*)x;
    int lane = threadIdx.x & 63;
    float v = 0.f;
    for (int i = lane; i < 256; i += 64) {
        float a = fabsf(__bfloat162float(p[i]));
        if (!(a <= 2.0f)) v = 1.f;
    }
    for (int off = 32; off; off >>= 1) v += __shfl_down(v, off, 64);
    if (lane == 0) {
        g_isbf16 = (v == 0.f) ? 1 : 0;
        g_ws[OFF_REC] = 0.f;
    }
}

// ---------------- weight pack: ext dtype -> g_wt fp32 + g_wp bf16 [t][n][k] ----------------
__global__ void wpack_k(const void* esw1, const void* esb1, const void* esw2, const void* esb2,
                        const void* eswp, const void* esbp, const void* eaw1, const void* eab1,
                        const void* eaw2, const void* eab2, const void* dw1, const void* db1,
                        const void* dw2, const void* db2, const void* dw3, const void* db3) {
    int bf = g_isbf16;
    int gid0 = blockIdx.x * 256 + threadIdx.x, stride = gridDim.x * 256;
    for (int g = gid0; g < 1728; g += stride) g_wt[WT_ESW1 + g] = ldin(esw1, g, bf);
    for (int g = gid0; g < 64; g += stride) g_wt[WT_ESB1 + g] = ldin(esb1, g, bf);
    for (int g = gid0; g < 64; g += stride) g_wt[WT_ESB2 + g] = ldin(esb2, g, bf);
    for (int g = gid0; g < 16; g += stride) g_wt[WT_ESBP + g] = ldin(esbp, g, bf);
    for (int g = gid0; g < 64; g += stride) g_wt[WT_EAB1 + g] = ldin(eab1, g, bf);
    for (int g = gid0; g < 32; g += stride) g_wt[WT_EAB2 + g] = ldin(eab2, g, bf);
    for (int g = gid0; g < 64; g += stride) g_wt[WT_DB1 + g] = ldin(db1, g, bf);
    for (int g = gid0; g < 32; g += stride) g_wt[WT_DB2 + g] = ldin(db2, g, bf);
    for (int g = gid0; g < 3; g += stride) g_wt[WT_DB3 + g] = ldin(db3, g, bf);
    for (int g = gid0; g < 864; g += stride) {              // w3p[t][o][k]
        int t = g / 96, o = (g / 32) % 3, k = g & 31;
        g_wt[WT_W3P + g] = ldin(dw3, (size_t)(o * 32 + k) * 9 + t, bf);
    }
    for (int g = gid0; g < 36864; g += stride) {            // wp2[t][n][k] from es_w2[n][k][t]
        int t = g >> 12, n = (g >> 6) & 63, k = g & 63;
        g_wp[P_WP2 + g] = __float2bfloat16(ldin(esw2, (size_t)(n * 64 + k) * 9 + t, bf));
    }
    for (int g = gid0; g < 9216; g += stride) {             // wpp[t][n<16][k]
        int t = g >> 10, n = (g >> 6) & 15, k = g & 63;
        g_wp[P_WPP + g] = __float2bfloat16(ldin(eswp, (size_t)(n * 64 + k) * 9 + t, bf));
    }
    for (int g = gid0; g < 36864; g += stride) {            // wpa1
        int t = g >> 12, n = (g >> 6) & 63, k = g & 63;
        g_wp[P_WPA1 + g] = __float2bfloat16(ldin(eaw1, (size_t)(n * 64 + k) * 9 + t, bf));
    }
    for (int g = gid0; g < 18432; g += stride) {            // wpa2[t][n<32][k]
        int t = g >> 11, n = (g >> 6) & 31, k = g & 63;
        g_wp[P_WPA2 + g] = __float2bfloat16(ldin(eaw2, (size_t)(n * 64 + k) * 9 + t, bf));
    }
    for (int g = gid0; g < 36864; g += stride) {            // wpd1: K=48 zero-padded to 64
        int t = g >> 12, n = (g >> 6) & 63, k = g & 63;
        float v = (k < 48) ? ldin(dw1, (size_t)(n * 48 + k) * 9 + t, bf) : 0.f;
        g_wp[P_WPD1 + g] = __float2bfloat16(v);
    }
    for (int g = gid0; g < 18432; g += stride) {            // wpd2[t][n<32][k]
        int t = g >> 11, n = (g >> 6) & 31, k = g & 63;
        g_wp[P_WPD2 + g] = __float2bfloat16(ldin(dw2, (size_t)(n * 64 + k) * 9 + t, bf));
    }
}

// ---------------- conv1 both streams: stride-2 -> NHWC bf16 [64,4096,64], relu ----
__global__ void __launch_bounds__(256)
conv_s2n_k(const void* __restrict__ inA, const void* __restrict__ inB) {
    int bf = g_isbf16;
    int tile = blockIdx.x & 15;
    int gb = blockIdx.x >> 4;
    int g = gb & 3, b = gb >> 2;
    const void* in = (b < 32) ? inA : inB;
    int bb = b & 31;
    int pix = tile * 256 + threadIdx.x;
    int y = pix >> 6, x = pix & 63;
    size_t inb = (size_t)bb * 3 * 16384;
    const float* W = g_wt + WT_ESW1 + (size_t)(g * 16) * 27;
    float acc[16];
    #pragma unroll
    for (int o = 0; o < 16; ++o) acc[o] = g_wt[WT_ESB1 + g * 16 + o];
    int iy0 = 2 * y, ix0 = 2 * x;
    bool my2 = (iy0 + 2 < 128), mx2 = (ix0 + 2 < 128);
    int iy2 = my2 ? iy0 + 2 : 127, ix2 = mx2 ? ix0 + 2 : 127;
    for (int ic = 0; ic < 3; ++ic) {
        size_t pb = inb + ic * 16384;
        float t[9];
        t[0] = ldin(in, pb + iy0 * 128 + ix0, bf);
        t[1] = ldin(in, pb + iy0 * 128 + ix0 + 1, bf);
        t[2] = selz(mx2, ldin(in, pb + iy0 * 128 + ix2, bf));
        t[3] = ldin(in, pb + (iy0 + 1) * 128 + ix0, bf);
        t[4] = ldin(in, pb + (iy0 + 1) * 128 + ix0 + 1, bf);
        t[5] = selz(mx2, ldin(in, pb + (iy0 + 1) * 128 + ix2, bf));
        t[6] = selz(my2, ldin(in, pb + iy2 * 128 + ix0, bf));
        t[7] = selz(my2, ldin(in, pb + iy2 * 128 + ix0 + 1, bf));
        t[8] = selz(my2 && mx2, ldin(in, pb + iy2 * 128 + ix2, bf));
        #pragma unroll
        for (int o = 0; o < 16; ++o) {
            const float* wr = W + (o * 3 + ic) * 9;
            float a = acc[o];
            #pragma unroll
            for (int j = 0; j < 9; ++j) a = fmaf(t[j], wr[j], a);
            acc[o] = a;
        }
    }
    __hip_bfloat16* out = (__hip_bfloat16*)g_ws + BA_XA + ((size_t)b * 4096 + pix) * 64 + g * 16;
    #pragma unroll
    for (int o = 0; o < 16; ++o) out[o] = __float2bfloat16(fmaxf(acc[o], 0.f));
}

// ---------------- LDS-staged MFMA 3x3 conv on 64x64 NHWC (Cin=64) ----------------
// Block = 4 waves = 4 consecutive rows of one batch. LDS tile: 6 halo rows x 66 px
// (1 zero-pad px each side) x 64 ch, 16B chunks swizzled (slot = j ^ (P&7)).
template<int TOTN, int NS, int OUTF32, int RELU>
__global__ void __launch_bounds__(256) __attribute__((amdgpu_waves_per_eu(2, 4)))
conv_mfl_k(size_t in_off, int wp_off, int bias_off, size_t out_off) {
    __shared__ __hip_bfloat16 sA[6 * 66 * 64];   // 50688 B -> 3 blocks/CU
    int wid = threadIdx.x >> 6, lane = threadIdx.x & 63;
    int l15 = lane & 15, quad = lane >> 4;
    int b = blockIdx.x >> 4, y0 = (blockIdx.x & 15) * 4;
    const __hip_bfloat16* inb = (const __hip_bfloat16*)g_ws + in_off + (size_t)b * 4096 * 64;
    for (int g = threadIdx.x; g < 3072; g += 256) {
        int r = g >> 9;                 // 0..5
        int rem = g & 511;
        int px = rem >> 3, j = rem & 7;
        int yy = y0 - 1 + r;
        int P = px + 1;
        bf8v v = (bf8v){0, 0, 0, 0, 0, 0, 0, 0};
        if (yy >= 0 && yy <= 63)
            v = *(const bf8v*)(inb + ((size_t)(yy * 64 + px) * 64 + j * 8));
        *(bf8v*)(sA + ((r * 66 + P) * 64 + ((j ^ (P & 7)) * 8))) = v;
    }
    if (threadIdx.x < 96) {             // zero pads P=0 and P=65
        int g = threadIdx.x;
        int r = g / 16, rem = g % 16, side = rem >> 3, j = rem & 7;
        int P = side ? 65 : 0;
        *(bf8v*)(sA + ((r * 66 + P) * 64 + ((j ^ (P & 7)) * 8))) = (bf8v){0, 0, 0, 0, 0, 0, 0, 0};
    }
    __syncthreads();
    int y = y0 + wid;
    f32x4 acc[4][NS];
    #pragma unroll
    for (int ms = 0; ms < 4; ++ms)
        #pragma unroll
        for (int ns = 0; ns < NS; ++ns) acc[ms][ns] = (f32x4){0.f, 0.f, 0.f, 0.f};
    #pragma unroll
    for (int t = 0; t < 9; ++t) {
        int dy = t / 3 - 1, dx = t % 3 - 1;
        int r = wid + 1 + dy;           // 0..5, always valid (halo pre-zeroed)
        #pragma unroll
        for (int c = 0; c < 2; ++c) {
            int j = c * 4 + quad;
            bf8v a[4];
            #pragma unroll
            for (int ms = 0; ms < 4; ++ms) {
                int P = ms * 16 + l15 + dx + 1;   // 0..65, always valid
                a[ms] = *(const bf8v*)(sA + ((r * 66 + P) * 64 + ((j ^ (P & 7)) * 8)));
            }
            #pragma unroll
            for (int ns = 0; ns < NS; ++ns) {
                bf8v bv = *(const bf8v*)(g_wp + wp_off +
                          ((size_t)(t * TOTN + ns * 16 + l15) * 64 + c * 32 + quad * 8));
                #pragma unroll
                for (int ms = 0; ms < 4; ++ms)
                    acc[ms][ns] = __builtin_amdgcn_mfma_f32_16x16x32_bf16(a[ms], bv, acc[ms][ns], 0, 0, 0);
            }
        }
    }
    #pragma unroll
    for (int ns = 0; ns < NS; ++ns) {
        float bias = g_wt[bias_off + ns * 16 + l15];
        #pragma unroll
        for (int ms = 0; ms < 4; ++ms) {
            #pragma unroll
            for (int r = 0; r < 4; ++r) {
                int pix = ms * 16 + quad * 4 + r;
                float v = acc[ms][ns][r] + bias;
                if (RELU) v = fmaxf(v, 0.f);
                size_t o = out_off + ((size_t)(b * 4096 + y * 64 + pix)) * TOTN + ns * 16 + l15;
                if (OUTF32) g_ws[o] = v;
                else ((__hip_bfloat16*)g_ws)[o] = __float2bfloat16(v);
            }
        }
    }
}

// ---------------- LDS-staged MFMA decoder conv2 + 2x nearest upsample ----------------
// Block = 4 waves = 4 consecutive OUTPUT rows; needs 4 input rows (yi = yy>>1 in
// [y0/2-1, y0/2+2]) x 66 px x 64 ch = 33792 B LDS. x-map P=(xx>>1)+1 with zero pads.
__global__ void __launch_bounds__(256) __attribute__((amdgpu_waves_per_eu(2, 4)))
conv_upmf2_k(size_t in_off, int wp_off, int bias_off, size_t out_off) {
    __shared__ __hip_bfloat16 sA[4 * 66 * 64];   // 33792 B -> 4 blocks/CU
    int wid = threadIdx.x >> 6, lane = threadIdx.x & 63;
    int l15 = lane & 15, quad = lane >> 4;
    int b = blockIdx.x >> 5, y0 = (blockIdx.x & 31) * 4;
    int ri0 = (y0 >> 1) - 1;
    const __hip_bfloat16* inb = (const __hip_bfloat16*)g_ws + in_off + (size_t)b * 4096 * 64;
    for (int g = threadIdx.x; g < 2048; g += 256) {
        int r = g >> 9;                 // 0..3
        int rem = g & 511;
        int px = rem >> 3, j = rem & 7;
        int yi = ri0 + r;
        int P = px + 1;
        bf8v v = (bf8v){0, 0, 0, 0, 0, 0, 0, 0};
        if (yi >= 0 && yi <= 63)
            v = *(const bf8v*)(inb + ((size_t)(yi * 64 + px) * 64 + j * 8));
        *(bf8v*)(sA + ((r * 66 + P) * 64 + ((j ^ (P & 7)) * 8))) = v;
    }
    if (threadIdx.x < 64) {             // zero pads P=0 and P=65 (4 rows x 2 sides x 8 chunks)
        int g = threadIdx.x;
        int r = g >> 4, rem = g & 15, side = rem >> 3, j = rem & 7;
        int P = side ? 65 : 0;
        *(bf8v*)(sA + ((r * 66 + P) * 64 + ((j ^ (P & 7)) * 8))) = (bf8v){0, 0, 0, 0, 0, 0, 0, 0};
    }
    __syncthreads();
    int y = y0 + wid;
    f32x4 acc[8][2];
    #pragma unroll
    for (int ms = 0; ms < 8; ++ms)
        #pragma unroll
        for (int ns = 0; ns < 2; ++ns) acc[ms][ns] = (f32x4){0.f, 0.f, 0.f, 0.f};
    #pragma unroll
    for (int t = 0; t < 9; ++t) {
        int dy = t / 3 - 1, dx = t % 3 - 1;
        int yy = y + dy;
        if (yy < 0 || yy > 127) continue;     // wave-uniform
        int r = (yy >> 1) - ri0;              // 0..3
        #pragma unroll
        for (int c = 0; c < 2; ++c) {
            int j = c * 4 + quad;
            bf8v a[8];
            #pragma unroll
            for (int ms = 0; ms < 8; ++ms) {
                int xx = ms * 16 + l15 + dx;
                int P = (xx < 0) ? 0 : ((xx > 127) ? 65 : ((xx >> 1) + 1));
                a[ms] = *(const bf8v*)(sA + ((r * 66 + P) * 64 + ((j ^ (P & 7)) * 8)));
            }
            #pragma unroll
            for (int ns = 0; ns < 2; ++ns) {
                bf8v bv = *(const bf8v*)(g_wp + wp_off +
                          ((size_t)(t * 32 + ns * 16 + l15) * 64 + c * 32 + quad * 8));
                #pragma unroll
                for (int ms = 0; ms < 8; ++ms)
                    acc[ms][ns] = __builtin_amdgcn_mfma_f32_16x16x32_bf16(a[ms], bv, acc[ms][ns], 0, 0, 0);
            }
        }
    }
    #pragma unroll
    for (int ns = 0; ns < 2; ++ns) {
        float bias = g_wt[bias_off + ns * 16 + l15];
        #pragma unroll
        for (int ms = 0; ms < 8; ++ms) {
            #pragma unroll
            for (int r = 0; r < 4; ++r) {
                int pix = ms * 16 + quad * 4 + r;
                float v = fmaxf(acc[ms][ns][r] + bias, 0.f);
                size_t o = out_off + ((size_t)(b * 16384 + y * 128 + pix)) * 32 + ns * 16 + l15;
                ((__hip_bfloat16*)g_ws)[o] = __float2bfloat16(v);
            }
        }
    }
}

// ---------------- fused softmax+moments: parts logits fp32 NHWC [64,4096,16] ----------------
__global__ void sm_mom3_k() {
    int bk = blockIdx.x;
    int b = bk >> 4, k = bk & 15;
    int app = (b >= 32);
    const float* P = g_ws + OFF_PARTSF + (size_t)b * 4096 * 16 + k;
    float r[16];
    #pragma unroll
    for (int j = 0; j < 16; ++j) r[j] = P[(size_t)(threadIdx.x + j * 256) * 16];
    float m = r[0];
    #pragma unroll
    for (int j = 1; j < 16; ++j) m = fmaxf(m, r[j]);
    m = block_max(m);
    float s = 0.f;
    #pragma unroll
    for (int j = 0; j < 16; ++j) { r[j] = __expf(r[j] - m); s += r[j]; }
    s = block_sum(s);
    float inv = 1.0f / s;
    float sy = 0, sx = 0, syy = 0, sxy = 0, sxx = 0;
    #pragma unroll
    for (int j = 0; j < 16; ++j) {
        float pv = r[j] * inv;
        int i = threadIdx.x + j * 256;
        if (app) g_ws[OFF_PROBS + ((size_t)(b - 32) * 16 + k) * 4096 + i] = pv;
        float gy = -1.0f + (i >> 6) * (2.0f / 63.0f);
        float gx = -1.0f + (i & 63) * (2.0f / 63.0f);
        sy += pv * gy; sx += pv * gx;
        syy += pv * gy * gy; sxy += pv * gy * gx; sxx += pv * gx * gx;
    }
    sy = block_sum(sy); sx = block_sum(sx);
    syy = block_sum(syy); sxy = block_sum(sxy); sxx = block_sum(sxx);
    if (threadIdx.x == 0) {
        float c00 = syy - sy * sy, c01 = sxy - sy * sx, c11 = sxx - sx * sx;
        float a = sqrtf(fmaxf(c00 + EPS, 1e-12f));
        float bb = c01 / (a + EPS);
        float cc = sqrtf(fmaxf(c11 - bb * bb, 0.f) + EPS);
        float det = a * cc;
        float sc = SCAL / (det + EPS);
        int idx = app ? ((b - 32) * 16 + k) : (b * 16 + k);
        int mu_off = app ? OFF_MUA : OFF_MU;
        int linv_off = app ? OFF_LINVA : OFF_LINV;
        g_ws[mu_off + idx * 2 + 0] = sy;
        g_ws[mu_off + idx * 2 + 1] = sx;
        g_ws[linv_off + idx * 4 + 0] = cc * sc;
        g_ws[linv_off + idx * 4 + 1] = 0.f;
        g_ws[linv_off + idx * 4 + 2] = -bb * sc;
        g_ws[linv_off + idx * 4 + 3] = a * sc;
    }
}

// ---------------- alpha[b,k,f] = sum_hw probs[b,k,hw] * fxs[b,hw,f] (both fp32) ----------------
__global__ void alpha2_k() {
    int bk = blockIdx.x;
    int b = bk >> 4;
    __shared__ float pl[4096];
    const float* pr = g_ws + OFF_PROBS + (size_t)bk * 4096;
    for (int i = threadIdx.x; i < 4096; i += 256) pl[i] = pr[i];
    __syncthreads();
    float acc[32];
    #pragma unroll
    for (int f = 0; f < 32; ++f) acc[f] = 0.f;
    for (int i = threadIdx.x; i < 4096; i += 256) {
        float pv = pl[i];
        const float* fp = g_ws + OFF_FXS + (size_t)(b * 4096 + i) * 32;
        #pragma unroll
        for (int f = 0; f < 32; ++f) acc[f] = fmaf(pv, fp[f], acc[f]);
    }
    __shared__ float sw[4][32];
    int lane = threadIdx.x & 63, wid = threadIdx.x >> 6;
    #pragma unroll
    for (int f = 0; f < 32; ++f)
        for (int off = 32; off; off >>= 1) acc[f] += __shfl_down(acc[f], off, 64);
    if (lane == 0) {
        #pragma unroll
        for (int f = 0; f < 32; ++f) sw[wid][f] = acc[f];
    }
    __syncthreads();
    if (threadIdx.x < 32)
        g_ws[OFF_ALPHA + bk * 32 + threadIdx.x] =
            sw[0][threadIdx.x] + sw[1][threadIdx.x] + sw[2][threadIdx.x] + sw[3][threadIdx.x];
}

// ---------------- heat -> E NHWC bf16 ch[0..16), + hsum ----------------
__global__ void heat2_k() {
    int bk = blockIdx.x;
    int b = bk >> 4, k = bk & 15;
    float m0 = g_ws[OFF_MU + bk * 2], m1 = g_ws[OFF_MU + bk * 2 + 1];
    float L00 = g_ws[OFF_LINV + bk * 4 + 0], L10 = g_ws[OFF_LINV + bk * 4 + 2],
          L11 = g_ws[OFF_LINV + bk * 4 + 3];
    __hip_bfloat16* E = (__hip_bfloat16*)g_ws + BA_E;
    float s = 0.f;
    for (int i = threadIdx.x; i < 4096; i += 256) {
        float d0 = -1.0f + (i >> 6) * (2.0f / 63.0f) - m0;
        float d1 = -1.0f + (i & 63) * (2.0f / 63.0f) - m1;
        float p0 = d0 * L00 + d1 * L10;
        float p1 = d1 * L11;
        float h = 1.0f / (1.0f + p0 * p0 + p1 * p1);
        E[(size_t)(b * 4096 + i) * 64 + k] = __float2bfloat16(h);
        s += h;
    }
    s = block_sum(s);
    if (threadIdx.x == 0) g_ws[OFF_HSUM + bk] = s;
}

// ---------------- fmap -> E ch[16..48), zero ch[48..64) ----------------
__global__ void fmap2_k() {
    int tile = blockIdx.x & 15, b = blockIdx.x >> 4;
    __shared__ float coef[16][32];
    for (int i = threadIdx.x; i < 512; i += 256) {
        int k = i >> 5, f = i & 31;
        coef[k][f] = g_ws[OFF_ALPHA + (b * 16 + k) * 32 + f] /
                     (g_ws[OFF_HSUM + b * 16 + k] + EPS);
    }
    __syncthreads();
    int pix = tile * 256 + threadIdx.x;
    __hip_bfloat16* E = (__hip_bfloat16*)g_ws + BA_E + (size_t)(b * 4096 + pix) * 64;
    float h[16];
    #pragma unroll
    for (int k = 0; k < 16; ++k) h[k] = __bfloat162float(E[k]);
    #pragma unroll
    for (int f = 0; f < 32; ++f) {
        float a = 0.f;
        #pragma unroll
        for (int k = 0; k < 16; ++k) a = fmaf(h[k], coef[k][f], a);
        E[16 + f] = __float2bfloat16(a);
    }
    #pragma unroll
    for (int z = 48; z < 64; ++z) E[z] = __float2bfloat16(0.f);
}

// ---------------- final conv(32->3) + sigmoid -> out, fused rec-loss; NHWC bf16 in ----------------
__global__ void __launch_bounds__(256)
conv_sign_k(const void* __restrict__ ximg, void* __restrict__ outp) {
    int bf = g_isbf16;
    int tile = blockIdx.x & 63, b = blockIdx.x >> 6;
    int pix = tile * 256 + threadIdx.x;
    int y = pix >> 7, x = pix & 127;
    const short* D2 = (const short*)((const __hip_bfloat16*)g_ws + BA_D2 + (size_t)b * 16384 * 32);
    float acc[3];
    #pragma unroll
    for (int o = 0; o < 3; ++o) acc[o] = g_wt[WT_DB3 + o];
    #pragma unroll
    for (int t = 0; t < 9; ++t) {
        int dy = t / 3 - 1, dx = t % 3 - 1;
        int yy = y + dy, xx = x + dx;
        if (yy < 0 || yy > 127 || xx < 0 || xx > 127) continue;
        const short* sp = D2 + (size_t)(yy * 128 + xx) * 32;
        #pragma unroll
        for (int c = 0; c < 4; ++c) {
            bf8v v = *(const bf8v*)(sp + c * 8);
            #pragma unroll
            for (int j = 0; j < 8; ++j) {
                float av = cvtbf(v[j]);
                int k = c * 8 + j;
                acc[0] = fmaf(av, g_wt[WT_W3P + (t * 3 + 0) * 32 + k], acc[0]);
                acc[1] = fmaf(av, g_wt[WT_W3P + (t * 3 + 1) * 32 + k], acc[1]);
                acc[2] = fmaf(av, g_wt[WT_W3P + (t * 3 + 2) * 32 + k], acc[2]);
            }
        }
    }
    float es = 0.f;
    #pragma unroll
    for (int o = 0; o < 3; ++o) {
        float v = 1.0f / (1.0f + __expf(-acc[o]));
        size_t oidx = ((size_t)b * 3 + o) * 16384 + pix;
        if (bf) ((__hip_bfloat16*)outp)[oidx] = __float2bfloat16(v);
        else    ((float*)outp)[oidx] = v;
        float e = ldin(ximg, oidx, bf) - v;
        es += e * e;
    }
    float s = block_sum(es);
    if (threadIdx.x == 0) atomicAdd(&g_ws[OFF_REC], s);
}

// ---------------- scalar loss ----------------
__global__ void loss_k(const void* __restrict__ coord,
                       const void* __restrict__ vec,
                       void* __restrict__ outp) {
    int bf = g_isbf16;
    const float* mu = g_ws + OFF_MU;
    const float* linv = g_ws + OFF_LINV;
    const float* mu_a = g_ws + OFF_MUA;
    const float* linv_a = g_ws + OFF_LINVA;
    float s1 = 0, s2 = 0, s3 = 0;
    for (int i = threadIdx.x; i < 1024; i += 256) {
        float d = mu[i] - mu_a[i];
        s1 += d * d;
        float t = ldin(coord, i, bf) + ldin(vec, i, bf);
        float d3 = mu_a[i] - t;
        s3 += d3 * d3;
    }
    for (int i = threadIdx.x; i < 2048; i += 256) {
        float d = linv[i] - linv_a[i];
        s2 += d * d;
    }
    s1 = block_sum(s1);
    s2 = block_sum(s2);
    s3 = block_sum(s3);
    if (threadIdx.x == 0) {
        float loss = g_ws[OFF_REC] / 1572864.0f + s1 / 1024.0f + 0.01f * (s2 / 2048.0f)
                   + s3 / 1024.0f;
        if (bf) ((__hip_bfloat16*)outp)[1572864] = __float2bfloat16(loss);
        else    ((float*)outp)[1572864] = loss;
    }
}

extern "C" void kernel_launch(void* const* d_in, const int* in_sizes, int n_in,
                              void* d_out, int out_size, void* d_ws, size_t ws_size,
                              hipStream_t stream) {
    const void* x     = d_in[0];
    const void* x_st  = d_in[1];
    const void* x_at  = d_in[2];
    const void* coord = d_in[3];
    const void* vec   = d_in[4];

    dim3 blk(256);

    detect_k<<<1, 64, 0, stream>>>(x);
    wpack_k<<<64, blk, 0, stream>>>(
        d_in[5],  d_in[6],  d_in[7],  d_in[8],
        d_in[9],  d_in[10], d_in[11], d_in[12],
        d_in[13], d_in[14], d_in[15], d_in[16],
        d_in[17], d_in[18], d_in[19], d_in[20]);

    // ---- encoder (B=64 batched, NHWC bf16): conv1 -> XA; conv2(MFMA+LDS) -> X2; parts ----
    conv_s2n_k<<<64 * 4 * 16, blk, 0, stream>>>(x_at, x_st);
    conv_mfl_k<64, 4, 0, 1><<<1024, blk, 0, stream>>>(BA_XA, P_WP2, WT_ESB2, BA_X2);
    conv_mfl_k<16, 1, 1, 0><<<1024, blk, 0, stream>>>(BA_X2, P_WPP, WT_ESBP, (size_t)OFF_PARTSF);
    sm_mom3_k<<<1024, blk, 0, stream>>>();

    // ---- e_alpha on app half -> FXS fp32; alpha ----
    conv_mfl_k<64, 4, 0, 1><<<512, blk, 0, stream>>>(BA_X2 + (size_t)32 * 4096 * 64, P_WPA1, WT_EAB1, BA_EA1);
    conv_mfl_k<32, 2, 1, 0><<<512, blk, 0, stream>>>(BA_EA1, P_WPA2, WT_EAB2, (size_t)OFF_FXS);
    alpha2_k<<<512, blk, 0, stream>>>();

    // ---- encoding E (NHWC bf16, 48+16pad): heat + fmap ----
    heat2_k<<<512, blk, 0, stream>>>();
    fmap2_k<<<512, blk, 0, stream>>>();

    // ---- decoder: dw1(MFMA+LDS) -> D1; upconv(MFMA+LDS) -> D2; sig conv -> out ----
    conv_mfl_k<64, 4, 0, 1><<<512, blk, 0, stream>>>(BA_E, P_WPD1, WT_DB1, BA_D1);
    conv_upmf2_k<<<1024, blk, 0, stream>>>(BA_D1, P_WPD2, WT_DB2, BA_D2);
    conv_sign_k<<<32 * 64, blk, 0, stream>>>(x, d_out);

    // ---- loss ----
    loss_k<<<1, blk, 0, stream>>>(coord, vec, d_out);
}